// Round 1
// baseline (6219.342 us; speedup 1.0000x reference)
//
#include <hip/hip_runtime.h>
#include <math.h>

#define D    2048
#define DC   512
#define DR   64
#define NH   16
#define HD   128
#define Bb   2
#define Tt   2048
#define ROWS (Bb*Tt)   // 4096

// ---------------- fp32 tiled GEMM: C[M,N] = A[M,K] @ B[K,N], row-major ----
// 64x64 tile, BK=16, 256 threads, 4x4 microtile. All dims here are multiples
// of tile sizes (M=4096, N in {2048,512,64}, K in {2048,512}) -> no guards.
__global__ __launch_bounds__(256)
void gemm_f32(const float* __restrict__ A, const float* __restrict__ B,
              float* __restrict__ C, int M, int N, int K) {
    __shared__ float As[16][68];   // [k][m], +4 pad keeps float4 alignment
    __shared__ float Bs[16][68];   // [k][n]
    const int bm = blockIdx.y * 64;
    const int bn = blockIdx.x * 64;
    const int tid = threadIdx.x;
    const int tm  = (tid >> 4) << 2;   // 0..60 step 4
    const int tn  = (tid & 15) << 2;   // 0..60 step 4
    const int lar = tid >> 2;          // A tile row 0..63
    const int lac = (tid & 3) << 2;    // A tile col 0..12 step 4
    const int lbr = tid >> 4;          // B tile k 0..15
    const int lbc = (tid & 15) << 2;   // B tile col 0..60 step 4

    float acc[4][4] = {{0.f,0.f,0.f,0.f},{0.f,0.f,0.f,0.f},
                       {0.f,0.f,0.f,0.f},{0.f,0.f,0.f,0.f}};

    for (int k0 = 0; k0 < K; k0 += 16) {
        float4 a = *(const float4*)(A + (size_t)(bm + lar) * K + (k0 + lac));
        As[lac + 0][lar] = a.x;
        As[lac + 1][lar] = a.y;
        As[lac + 2][lar] = a.z;
        As[lac + 3][lar] = a.w;
        *(float4*)&Bs[lbr][lbc] =
            *(const float4*)(B + (size_t)(k0 + lbr) * N + (bn + lbc));
        __syncthreads();
        #pragma unroll
        for (int k = 0; k < 16; ++k) {
            float4 a4 = *(float4*)&As[k][tm];
            float4 b4 = *(float4*)&Bs[k][tn];
            float av[4] = {a4.x, a4.y, a4.z, a4.w};
            float bv[4] = {b4.x, b4.y, b4.z, b4.w};
            #pragma unroll
            for (int i = 0; i < 4; ++i)
                #pragma unroll
                for (int j = 0; j < 4; ++j)
                    acc[i][j] += av[i] * bv[j];
        }
        __syncthreads();
    }
    #pragma unroll
    for (int i = 0; i < 4; ++i) {
        float4 o = make_float4(acc[i][0], acc[i][1], acc[i][2], acc[i][3]);
        *(float4*)(C + (size_t)(bm + tm + i) * N + (bn + tn)) = o;
    }
}

// ---------------- RoPE in place on (ROWS, 64); row -> t = row % Tt ---------
__global__ void rope_kernel(float* __restrict__ p) {
    int idx = blockIdx.x * blockDim.x + threadIdx.x;
    if (idx >= ROWS * 32) return;
    int row = idx >> 5;
    int i   = idx & 31;
    int t   = row & (Tt - 1);
    float inv  = powf(10000.0f, -(float)(2 * i) / 64.0f);
    float freq = (float)t * inv;
    float c = cosf(freq), s = sinf(freq);
    float* v = p + (size_t)row * DR;
    float x1 = v[i], x2 = v[i + 32];
    v[i]      = x1 * c - x2 * s;
    v[i + 32] = x2 * c + x1 * s;
}

// ---------------- entry = concat([ckv, kr_roped], -1) -> (ROWS, 576) -------
__global__ void entry_kernel(const float* __restrict__ ckv,
                             const float* __restrict__ kr,
                             float* __restrict__ ent) {
    int idx = blockIdx.x * blockDim.x + threadIdx.x;
    if (idx >= ROWS * (DC + DR)) return;
    int row = idx / (DC + DR);
    int c   = idx % (DC + DR);
    ent[idx] = (c < DC) ? ckv[(size_t)row * DC + c]
                        : kr[(size_t)row * DR + (c - DC)];
}

// ---------------- flash attention with rope-score term ---------------------
// q,k,v: (B,T,D) with head h at cols h*HD..  qr,kr: (B*T, DR) roped.
// scores = (q.k + qr.kr)/sqrt(HD+DR), causal (key s <= query t), softmax, @v.
#define BQ 64
#define BK 32
__global__ __launch_bounds__(256)
void attn_kernel(const float* __restrict__ q, const float* __restrict__ k,
                 const float* __restrict__ v, const float* __restrict__ qr,
                 const float* __restrict__ kr, float* __restrict__ out) {
    __shared__ float Qs[BQ][HD];       // 32 KB
    __shared__ float QRs[BQ][DR];      // 16 KB
    __shared__ float Ks[BK][HD];       // 16 KB
    __shared__ float KRs[BK][DR];      //  8 KB
    __shared__ float Vs[BK][HD];       // 16 KB
    __shared__ float Ss[BQ][BK + 1];   // ~8.4 KB   (total ~97 KB: 1 block/CU)

    const int q0  = blockIdx.x * BQ;
    const int h   = blockIdx.y;
    const int b   = blockIdx.z;
    const int tid = threadIdx.x;
    const int r   = tid >> 2;          // query row in tile (0..63)
    const int jg  = (tid & 3) << 3;    // S col group base (8 cols)
    const int cg  = (tid & 3) << 5;    // O col group base (32 cols)

    const size_t base_q  = ((size_t)b * Tt + q0) * D + (size_t)h * HD;
    const size_t base_qr = ((size_t)b * Tt + q0) * DR;
    for (int idx = tid; idx < BQ * (HD / 4); idx += 256) {
        int rr = idx / (HD / 4), c4 = (idx % (HD / 4)) * 4;
        *(float4*)&Qs[rr][c4] = *(const float4*)(q + base_q + (size_t)rr * D + c4);
    }
    for (int idx = tid; idx < BQ * (DR / 4); idx += 256) {
        int rr = idx / (DR / 4), c4 = (idx % (DR / 4)) * 4;
        *(float4*)&QRs[rr][c4] = *(const float4*)(qr + base_qr + (size_t)rr * DR + c4);
    }

    float m_prev = -1e30f, l = 0.0f;
    float acc[32];
    #pragma unroll
    for (int c = 0; c < 32; ++c) acc[c] = 0.0f;
    const float rscale = 0.07216878364870323f;  // 1/sqrt(HD+DR)=1/sqrt(192)

    for (int s0 = 0; s0 < q0 + BQ; s0 += BK) {
        __syncthreads();   // also covers initial Q staging
        const size_t base_k  = ((size_t)b * Tt + s0) * D + (size_t)h * HD;
        const size_t base_kr = ((size_t)b * Tt + s0) * DR;
        for (int idx = tid; idx < BK * (HD / 4); idx += 256) {
            int jj = idx / (HD / 4), c4 = (idx % (HD / 4)) * 4;
            *(float4*)&Ks[jj][c4] = *(const float4*)(k + base_k + (size_t)jj * D + c4);
            *(float4*)&Vs[jj][c4] = *(const float4*)(v + base_k + (size_t)jj * D + c4);
        }
        for (int idx = tid; idx < BK * (DR / 4); idx += 256) {
            int jj = idx / (DR / 4), c4 = (idx % (DR / 4)) * 4;
            *(float4*)&KRs[jj][c4] = *(const float4*)(kr + base_kr + (size_t)jj * DR + c4);
        }
        __syncthreads();

        // S tile: each thread computes 8 dots for its row
        float dot[8];
        #pragma unroll
        for (int jo = 0; jo < 8; ++jo) dot[jo] = 0.0f;
        for (int c = 0; c < HD; c += 4) {
            float4 qv = *(float4*)&Qs[r][c];
            #pragma unroll
            for (int jo = 0; jo < 8; ++jo) {
                float4 kv = *(float4*)&Ks[jg + jo][c];
                dot[jo] += qv.x * kv.x + qv.y * kv.y + qv.z * kv.z + qv.w * kv.w;
            }
        }
        for (int c = 0; c < DR; c += 4) {
            float4 qv = *(float4*)&QRs[r][c];
            #pragma unroll
            for (int jo = 0; jo < 8; ++jo) {
                float4 kv = *(float4*)&KRs[jg + jo][c];
                dot[jo] += qv.x * kv.x + qv.y * kv.y + qv.z * kv.z + qv.w * kv.w;
            }
        }
        #pragma unroll
        for (int jo = 0; jo < 8; ++jo) {
            int j = jg + jo;
            float sv = dot[jo] * rscale;
            if (s0 + j > q0 + r) sv = -1e30f;   // causal mask
            Ss[r][j] = sv;
        }
        __syncthreads();

        // online softmax update (4 threads/row compute identical state)
        float m_tile = -1e30f;
        for (int j = 0; j < BK; ++j) m_tile = fmaxf(m_tile, Ss[r][j]);
        float m_new  = fmaxf(m_prev, m_tile);
        float alpha  = __expf(m_prev - m_new);
        #pragma unroll
        for (int jo = 0; jo < 8; ++jo) {
            int j = jg + jo;
            Ss[r][j] = __expf(Ss[r][j] - m_new);
        }
        __syncthreads();
        float rowsum = 0.0f;
        for (int j = 0; j < BK; ++j) rowsum += Ss[r][j];
        l = l * alpha + rowsum;
        m_prev = m_new;

        // O update: this thread owns row r, cols cg..cg+31
        #pragma unroll
        for (int c = 0; c < 32; ++c) acc[c] *= alpha;
        for (int j = 0; j < BK; ++j) {
            float pj = Ss[r][j];
            #pragma unroll
            for (int c4 = 0; c4 < 32; c4 += 4) {
                float4 vv = *(float4*)&Vs[j][cg + c4];
                acc[c4 + 0] += pj * vv.x;
                acc[c4 + 1] += pj * vv.y;
                acc[c4 + 2] += pj * vv.z;
                acc[c4 + 3] += pj * vv.w;
            }
        }
    }

    float inv_l = 1.0f / l;
    float* op = out + ((size_t)b * Tt + (q0 + r)) * D + (size_t)h * HD + cg;
    #pragma unroll
    for (int c = 0; c < 32; ++c) op[c] = acc[c] * inv_l;
}

extern "C" void kernel_launch(void* const* d_in, const int* in_sizes, int n_in,
                              void* d_out, int out_size, void* d_ws, size_t ws_size,
                              hipStream_t stream) {
    const float* x    = (const float*)d_in[0];
    const float* Wkv  = (const float*)d_in[1];
    const float* Wkup = (const float*)d_in[2];
    const float* Wvup = (const float*)d_in[3];
    const float* Wq   = (const float*)d_in[4];
    const float* Wqr  = (const float*)d_in[5];
    const float* Wkr  = (const float*)d_in[6];
    const float* Wo   = (const float*)d_in[7];

    float* out0 = (float*)d_out;                     // (4096, 2048) attn proj
    float* out1 = out0 + (size_t)ROWS * D;           // (4096, 576) entry

    float* ws  = (float*)d_ws;
    float* ckv = ws; ws += (size_t)ROWS * DC;        //  8 MB
    float* kr  = ws; ws += (size_t)ROWS * DR;        //  1 MB
    float* qr  = ws; ws += (size_t)ROWS * DR;        //  1 MB
    float* q   = ws; ws += (size_t)ROWS * D;         // 33.5 MB
    float* k   = ws; ws += (size_t)ROWS * D;         // 33.5 MB
    float* v   = ws; ws += (size_t)ROWS * D;         // 33.5 MB
    float* ao  = ws; ws += (size_t)ROWS * D;         // 33.5 MB (total ~145 MB)

    dim3 blk(256);

    // ckv = x @ Wkv
    gemm_f32<<<dim3(DC / 64, ROWS / 64), blk, 0, stream>>>(x, Wkv, ckv, ROWS, DC, D);
    // kr = rope(ckv @ Wkr)
    gemm_f32<<<dim3(DR / 64, ROWS / 64), blk, 0, stream>>>(ckv, Wkr, kr, ROWS, DR, DC);
    rope_kernel<<<(ROWS * 32 + 255) / 256, blk, 0, stream>>>(kr);
    // entry output
    entry_kernel<<<(ROWS * (DC + DR) + 255) / 256, blk, 0, stream>>>(ckv, kr, out1);
    // q = x @ Wq ; qr = rope(x @ Wqr)
    gemm_f32<<<dim3(D / 64, ROWS / 64), blk, 0, stream>>>(x, Wq, q, ROWS, D, D);
    gemm_f32<<<dim3(DR / 64, ROWS / 64), blk, 0, stream>>>(x, Wqr, qr, ROWS, DR, D);
    rope_kernel<<<(ROWS * 32 + 255) / 256, blk, 0, stream>>>(qr);
    // k = ckv @ Wkup ; v = ckv @ Wvup   (stored (B,T,D) = (B,T,NH,HD))
    gemm_f32<<<dim3(D / 64, ROWS / 64), blk, 0, stream>>>(ckv, Wkup, k, ROWS, D, DC);
    gemm_f32<<<dim3(D / 64, ROWS / 64), blk, 0, stream>>>(ckv, Wvup, v, ROWS, D, DC);
    // attention
    attn_kernel<<<dim3(Tt / BQ, NH, Bb), blk, 0, stream>>>(q, k, v, qr, kr, ao);
    // out0 = ao @ Wo
    gemm_f32<<<dim3(D / 64, ROWS / 64), blk, 0, stream>>>(ao, Wo, out0, ROWS, D, D);
}

// Round 2
// 1912.849 us; speedup vs baseline: 3.2514x; 3.2514x over previous
//
#include <hip/hip_runtime.h>
#include <math.h>
#include <type_traits>

#define D    2048
#define DC   512
#define DR   64
#define NH   16
#define HD   128
#define Bb   2
#define Tt   2048
#define ROWS (Bb*Tt)   // 4096

typedef __bf16 bf16x8 __attribute__((ext_vector_type(8)));
typedef float  f32x4  __attribute__((ext_vector_type(4)));

// ---------------- fp32 tiled GEMM: C[M,N] = A[M,K] @ B[K,N], row-major ----
// 64x64 tile, BK=16, 256 threads, 4x4 microtile. OutT in {float, __bf16}.
template <typename OutT>
__global__ __launch_bounds__(256)
void gemm_t(const float* __restrict__ A, const float* __restrict__ B,
            OutT* __restrict__ C, int M, int N, int K) {
    __shared__ float As[16][68];
    __shared__ float Bs[16][68];
    const int bm = blockIdx.y * 64;
    const int bn = blockIdx.x * 64;
    const int tid = threadIdx.x;
    const int tm  = (tid >> 4) << 2;
    const int tn  = (tid & 15) << 2;
    const int lar = tid >> 2;
    const int lac = (tid & 3) << 2;
    const int lbr = tid >> 4;
    const int lbc = (tid & 15) << 2;

    float acc[4][4] = {{0.f,0.f,0.f,0.f},{0.f,0.f,0.f,0.f},
                       {0.f,0.f,0.f,0.f},{0.f,0.f,0.f,0.f}};

    for (int k0 = 0; k0 < K; k0 += 16) {
        float4 a = *(const float4*)(A + (size_t)(bm + lar) * K + (k0 + lac));
        As[lac + 0][lar] = a.x;
        As[lac + 1][lar] = a.y;
        As[lac + 2][lar] = a.z;
        As[lac + 3][lar] = a.w;
        *(float4*)&Bs[lbr][lbc] =
            *(const float4*)(B + (size_t)(k0 + lbr) * N + (bn + lbc));
        __syncthreads();
        #pragma unroll
        for (int k = 0; k < 16; ++k) {
            float4 a4 = *(float4*)&As[k][tm];
            float4 b4 = *(float4*)&Bs[k][tn];
            float av[4] = {a4.x, a4.y, a4.z, a4.w};
            float bv[4] = {b4.x, b4.y, b4.z, b4.w};
            #pragma unroll
            for (int i = 0; i < 4; ++i)
                #pragma unroll
                for (int j = 0; j < 4; ++j)
                    acc[i][j] += av[i] * bv[j];
        }
        __syncthreads();
    }
    #pragma unroll
    for (int i = 0; i < 4; ++i) {
        if constexpr (std::is_same<OutT, float>::value) {
            float4 o = make_float4(acc[i][0], acc[i][1], acc[i][2], acc[i][3]);
            *(float4*)(C + (size_t)(bm + tm + i) * N + (bn + tn)) = o;
        } else {
            OutT* p = C + (size_t)(bm + tm + i) * N + (bn + tn);
            #pragma unroll
            for (int j = 0; j < 4; ++j) p[j] = (OutT)acc[i][j];
        }
    }
}

// ---------------- RoPE in place on (ROWS, 64) fp32 ------------------------
__global__ void rope_kernel(float* __restrict__ p) {
    int idx = blockIdx.x * blockDim.x + threadIdx.x;
    if (idx >= ROWS * 32) return;
    int row = idx >> 5;
    int i   = idx & 31;
    int t   = row & (Tt - 1);
    float inv  = powf(10000.0f, -(float)(2 * i) / 64.0f);
    float freq = (float)t * inv;
    float c = cosf(freq), s = sinf(freq);
    float* v = p + (size_t)row * DR;
    float x1 = v[i], x2 = v[i + 32];
    v[i]      = x1 * c - x2 * s;
    v[i + 32] = x2 * c + x1 * s;
}

// ---------------- fp32 -> bf16 convert ------------------------------------
__global__ void f32_to_bf16(const float* __restrict__ in,
                            __bf16* __restrict__ out, int n) {
    int i = blockIdx.x * blockDim.x + threadIdx.x;
    if (i < n) out[i] = (__bf16)in[i];
}

// ---------------- entry = concat([ckv, kr_roped], -1) -> (ROWS, 576) ------
__global__ void entry_kernel(const float* __restrict__ ckv,
                             const float* __restrict__ kr,
                             float* __restrict__ ent) {
    int idx = blockIdx.x * blockDim.x + threadIdx.x;
    if (idx >= ROWS * (DC + DR)) return;
    int row = idx / (DC + DR);
    int c   = idx % (DC + DR);
    ent[idx] = (c < DC) ? ckv[(size_t)row * DC + c]
                        : kr[(size_t)row * DR + (c - DC)];
}

// ---------------- V transpose: vb[B][T][D] -> vtb[B][D][T] (bf16) ---------
__global__ __launch_bounds__(256)
void transpose_v(const __bf16* __restrict__ vb, __bf16* __restrict__ vtb) {
    __shared__ __bf16 tile[64][65];
    const int t0 = blockIdx.x * 64;
    const int c0 = blockIdx.y * 64;
    const int b  = blockIdx.z;
    const int tid = threadIdx.x;
    for (int e = tid; e < 64 * 64; e += 256) {
        int i = e >> 6, j = e & 63;       // i: t, j: c  (j fastest: coalesced)
        tile[i][j] = vb[((size_t)(b * Tt + t0 + i)) * D + c0 + j];
    }
    __syncthreads();
    for (int e = tid; e < 64 * 64; e += 256) {
        int i = e >> 6, j = e & 63;       // i: c, j: t  (j fastest: coalesced)
        vtb[((size_t)(b * D + c0 + i)) * Tt + t0 + j] = tile[j][i];
    }
}

// ---------------- MFMA flash attention ------------------------------------
// qb,kb: (B,T,D) bf16 (head h at cols h*HD); qrb,krb: (B*T,DR) bf16 roped;
// vtb: (B, D, T) bf16 = V transposed per (b, col).
// Strides chosen so row stride ≡ 4 dwords (mod 32): uniform bank groups.
#define QS_STR 200
#define VT_STR 72
#define PS_STR 72

__global__ __launch_bounds__(256)
void attn_mfma(const __bf16* __restrict__ qb, const __bf16* __restrict__ kb,
               const __bf16* __restrict__ vtb, const __bf16* __restrict__ qrb,
               const __bf16* __restrict__ krb, float* __restrict__ out) {
    __shared__ __bf16 Qs[64][QS_STR];      // 25.6 KB  (cols 0..127 q, 128..191 qr)
    __shared__ __bf16 Ks[64][QS_STR];      // 25.6 KB
    __shared__ __bf16 Vt[128][VT_STR];     // 18.4 KB  Vt[n][key]
    __shared__ __bf16 Ps[4][16][PS_STR];   //  9.2 KB  per-wave P tile

    const int tid  = threadIdx.x;
    const int w    = tid >> 6;     // wave 0..3 -> q rows w*16..w*16+15
    const int lane = tid & 63;
    const int quad = lane >> 4;
    const int lc   = lane & 15;
    const int q0   = blockIdx.x * 64;
    const int h    = blockIdx.y;
    const int b    = blockIdx.z;

    // stage Q tile once
    {
        const __bf16* qbase = qb + ((size_t)(b * Tt + q0)) * D + h * HD;
        for (int c = tid; c < 64 * 16; c += 256) {
            int row = c >> 4, c8 = c & 15;
            *(bf16x8*)&Qs[row][c8 * 8] =
                *(const bf16x8*)(qbase + (size_t)row * D + c8 * 8);
        }
        const __bf16* qrbase = qrb + ((size_t)(b * Tt + q0)) * DR;
        for (int c = tid; c < 64 * 8; c += 256) {
            int row = c >> 3, c8 = c & 7;
            *(bf16x8*)&Qs[row][128 + c8 * 8] =
                *(const bf16x8*)(qrbase + (size_t)row * DR + c8 * 8);
        }
    }

    float m_i[4], l_i[4];
    f32x4 Of[8];
    #pragma unroll
    for (int r = 0; r < 4; ++r) { m_i[r] = -1e30f; l_i[r] = 0.f; }
    #pragma unroll
    for (int n = 0; n < 8; ++n) Of[n] = (f32x4){0.f, 0.f, 0.f, 0.f};

    const int ntiles = blockIdx.x + 1;
    const float rscale = 0.07216878364870323f;   // 1/sqrt(192)
    const int qrow = q0 + w * 16 + quad * 4;     // + r

    for (int it = 0; it < ntiles; ++it) {
        const int s0 = it * 64;
        __syncthreads();
        // stage K tile (kb cols + krb cols)
        const __bf16* kbase = kb + ((size_t)(b * Tt + s0)) * D + h * HD;
        for (int c = tid; c < 64 * 16; c += 256) {
            int row = c >> 4, c8 = c & 15;
            *(bf16x8*)&Ks[row][c8 * 8] =
                *(const bf16x8*)(kbase + (size_t)row * D + c8 * 8);
        }
        const __bf16* krbase = krb + ((size_t)(b * Tt + s0)) * DR;
        for (int c = tid; c < 64 * 8; c += 256) {
            int row = c >> 3, c8 = c & 7;
            *(bf16x8*)&Ks[row][128 + c8 * 8] =
                *(const bf16x8*)(krbase + (size_t)row * DR + c8 * 8);
        }
        // stage Vt tile: Vt[n][j] = V[s0+j][n] from vtb (contiguous in t)
        const __bf16* vbase = vtb + ((size_t)(b * D + h * HD)) * Tt + s0;
        for (int c = tid; c < 128 * 8; c += 256) {
            int n = c >> 3, c8 = c & 7;
            *(bf16x8*)&Vt[n][c8 * 8] =
                *(const bf16x8*)(vbase + (size_t)n * Tt + c8 * 8);
        }
        __syncthreads();

        // S = Q K^T  (4 col-frags of 16 keys, K-dim 192 = 6 steps)
        f32x4 sc[4];
        #pragma unroll
        for (int f = 0; f < 4; ++f) sc[f] = (f32x4){0.f, 0.f, 0.f, 0.f};
        #pragma unroll
        for (int kt = 0; kt < 6; ++kt) {
            bf16x8 aq = *(bf16x8*)&Qs[w * 16 + lc][kt * 32 + quad * 8];
            #pragma unroll
            for (int f = 0; f < 4; ++f) {
                bf16x8 bk = *(bf16x8*)&Ks[f * 16 + lc][kt * 32 + quad * 8];
                sc[f] = __builtin_amdgcn_mfma_f32_16x16x32_bf16(aq, bk, sc[f], 0, 0, 0);
            }
        }

        // online softmax. lane holds rows quad*4+r, col f*16+lc.
        float pv[4][4], mt[4];
        #pragma unroll
        for (int r = 0; r < 4; ++r) mt[r] = -1e30f;
        const bool need_mask = (s0 == q0);   // only the diagonal tile masks
        #pragma unroll
        for (int f = 0; f < 4; ++f) {
            #pragma unroll
            for (int r = 0; r < 4; ++r) {
                float sv = sc[f][r] * rscale;
                if (need_mask && (s0 + f * 16 + lc > qrow + r)) sv = -1e30f;
                pv[f][r] = sv;
                mt[r] = fmaxf(mt[r], sv);
            }
        }
        #pragma unroll
        for (int off = 1; off < 16; off <<= 1)
            #pragma unroll
            for (int r = 0; r < 4; ++r)
                mt[r] = fmaxf(mt[r], __shfl_xor(mt[r], off, 64));
        float alpha[4], rs[4];
        #pragma unroll
        for (int r = 0; r < 4; ++r) {
            float mn = fmaxf(m_i[r], mt[r]);
            alpha[r] = __expf(m_i[r] - mn);
            m_i[r] = mn;
            rs[r] = 0.f;
        }
        #pragma unroll
        for (int f = 0; f < 4; ++f) {
            #pragma unroll
            for (int r = 0; r < 4; ++r) {
                __bf16 pb = (__bf16)__expf(pv[f][r] - m_i[r]);
                Ps[w][quad * 4 + r][f * 16 + lc] = pb;
                rs[r] += (float)pb;          // sum the rounded values
            }
        }
        #pragma unroll
        for (int off = 1; off < 16; off <<= 1)
            #pragma unroll
            for (int r = 0; r < 4; ++r)
                rs[r] += __shfl_xor(rs[r], off, 64);
        #pragma unroll
        for (int r = 0; r < 4; ++r) l_i[r] = l_i[r] * alpha[r] + rs[r];
        #pragma unroll
        for (int n = 0; n < 8; ++n)
            #pragma unroll
            for (int r = 0; r < 4; ++r) Of[n][r] *= alpha[r];

        __syncthreads();   // Ps write -> cross-lane read (safe ordering)

        // O += P V   (A = P from LDS round-trip, B = Vt contiguous reads)
        #pragma unroll
        for (int kt = 0; kt < 2; ++kt) {
            bf16x8 ap = *(bf16x8*)&Ps[w][lc][kt * 32 + quad * 8];
            #pragma unroll
            for (int n = 0; n < 8; ++n) {
                bf16x8 bv = *(bf16x8*)&Vt[n * 16 + lc][kt * 32 + quad * 8];
                Of[n] = __builtin_amdgcn_mfma_f32_16x16x32_bf16(ap, bv, Of[n], 0, 0, 0);
            }
        }
    }

    // epilogue: O[row][col] at row=quad*4+r, col=n*16+lc
    float* obase = out + ((size_t)(b * Tt + q0 + w * 16 + quad * 4)) * D + h * HD + lc;
    #pragma unroll
    for (int r = 0; r < 4; ++r) {
        float inv = 1.0f / l_i[r];
        #pragma unroll
        for (int n = 0; n < 8; ++n)
            obase[(size_t)r * D + n * 16] = Of[n][r] * inv;
    }
}

extern "C" void kernel_launch(void* const* d_in, const int* in_sizes, int n_in,
                              void* d_out, int out_size, void* d_ws, size_t ws_size,
                              hipStream_t stream) {
    const float* x    = (const float*)d_in[0];
    const float* Wkv  = (const float*)d_in[1];
    const float* Wkup = (const float*)d_in[2];
    const float* Wvup = (const float*)d_in[3];
    const float* Wq   = (const float*)d_in[4];
    const float* Wqr  = (const float*)d_in[5];
    const float* Wkr  = (const float*)d_in[6];
    const float* Wo   = (const float*)d_in[7];

    float* out0 = (float*)d_out;                     // (4096, 2048)
    float* out1 = out0 + (size_t)ROWS * D;           // (4096, 576) entry

    char* wsb = (char*)d_ws;
    float*  ckv = (float*)wsb;                 wsb += (size_t)ROWS * DC * 4;   //  8 MB
    float*  krf = (float*)wsb;                 wsb += (size_t)ROWS * DR * 4;   //  1 MB
    float*  qrf = (float*)wsb;                 wsb += (size_t)ROWS * DR * 4;   //  1 MB
    float*  ao  = (float*)wsb;                 wsb += (size_t)ROWS * D  * 4;   // 33.5 MB
    __bf16* qb  = (__bf16*)wsb;                wsb += (size_t)ROWS * D  * 2;   // 16.8 MB
    __bf16* kb  = (__bf16*)wsb;                wsb += (size_t)ROWS * D  * 2;
    __bf16* vb  = (__bf16*)wsb;                wsb += (size_t)ROWS * D  * 2;
    __bf16* vtb = (__bf16*)wsb;                wsb += (size_t)ROWS * D  * 2;
    __bf16* qrb = (__bf16*)wsb;                wsb += (size_t)ROWS * DR * 2;
    __bf16* krb = (__bf16*)wsb;                wsb += (size_t)ROWS * DR * 2;

    dim3 blk(256);

    // ckv = x @ Wkv
    gemm_t<float><<<dim3(DC / 64, ROWS / 64), blk, 0, stream>>>(x, Wkv, ckv, ROWS, DC, D);
    // krf = rope(ckv @ Wkr); krb = bf16(krf)
    gemm_t<float><<<dim3(DR / 64, ROWS / 64), blk, 0, stream>>>(ckv, Wkr, krf, ROWS, DR, DC);
    rope_kernel<<<(ROWS * 32 + 255) / 256, blk, 0, stream>>>(krf);
    f32_to_bf16<<<(ROWS * DR + 255) / 256, blk, 0, stream>>>(krf, krb, ROWS * DR);
    // entry output
    entry_kernel<<<(ROWS * (DC + DR) + 255) / 256, blk, 0, stream>>>(ckv, krf, out1);
    // qb = bf16(x @ Wq); qrf = rope(x @ Wqr); qrb = bf16(qrf)
    gemm_t<__bf16><<<dim3(D / 64, ROWS / 64), blk, 0, stream>>>(x, Wq, qb, ROWS, D, D);
    gemm_t<float><<<dim3(DR / 64, ROWS / 64), blk, 0, stream>>>(x, Wqr, qrf, ROWS, DR, D);
    rope_kernel<<<(ROWS * 32 + 255) / 256, blk, 0, stream>>>(qrf);
    f32_to_bf16<<<(ROWS * DR + 255) / 256, blk, 0, stream>>>(qrf, qrb, ROWS * DR);
    // kb = bf16(ckv @ Wkup); vb = bf16(ckv @ Wvup); vtb = transpose(vb)
    gemm_t<__bf16><<<dim3(D / 64, ROWS / 64), blk, 0, stream>>>(ckv, Wkup, kb, ROWS, D, DC);
    gemm_t<__bf16><<<dim3(D / 64, ROWS / 64), blk, 0, stream>>>(ckv, Wvup, vb, ROWS, D, DC);
    transpose_v<<<dim3(Tt / 64, D / 64, Bb), blk, 0, stream>>>(vb, vtb);
    // attention -> ao (fp32)
    attn_mfma<<<dim3(Tt / 64, NH, Bb), blk, 0, stream>>>(qb, kb, vtb, qrb, krb, ao);
    // out0 = ao @ Wo
    gemm_t<float><<<dim3(D / 64, ROWS / 64), blk, 0, stream>>>(ao, Wo, out0, ROWS, D, D);
}

// Round 3
// 856.937 us; speedup vs baseline: 7.2576x; 2.2322x over previous
//
#include <hip/hip_runtime.h>
#include <math.h>
#include <type_traits>

#define D    2048
#define DC   512
#define DR   64
#define NH   16
#define HD   128
#define Bb   2
#define Tt   2048
#define ROWS (Bb*Tt)   // 4096

typedef __bf16 bf16x8 __attribute__((ext_vector_type(8)));
typedef float  f32x4  __attribute__((ext_vector_type(4)));

typedef const void __attribute__((address_space(1))) gvoid;
typedef void       __attribute__((address_space(3))) lvoid;

__device__ __forceinline__ void load_lds16(const void* g, void* l) {
    // 16B per lane, LDS dst = wave-uniform base + lane*16
    __builtin_amdgcn_global_load_lds((gvoid*)g, (lvoid*)l, 16, 0, 0);
}

// ============ bf16 MFMA GEMM: C[M,N] = A[M,K] @ BT[N,K]^T ==================
// m97 structure: 128x128 tile, BK=32, 4 waves, 4x4 16x16x32 accs/wave,
// global_load_lds width-16 staging. M%128==0, N%128==0, K%32==0.
template <bool WF32, bool WBF16>
__global__ __launch_bounds__(256)
void gemm_bt(const __bf16* __restrict__ A, const __bf16* __restrict__ BT,
             float* __restrict__ Cf, __bf16* __restrict__ Cb,
             int M, int N, int K) {
    __shared__ __bf16 As[128 * 32];   // 8 KB, row-major [row][k], stride 32
    __shared__ __bf16 Bs[128 * 32];   // 8 KB, [n][k]

    const int tid  = threadIdx.x;
    const int w    = tid >> 6;
    const int lane = tid & 63;
    const int quad = lane >> 4;
    const int lc   = lane & 15;
    const int bm   = blockIdx.y * 128;
    const int bn   = blockIdx.x * 128;
    const int wm   = (w & 1) * 64;
    const int wn   = (w >> 1) * 64;

    // staging: wave w owns rows w*32..w*32+31 of both tiles (2 instrs each)
    const int sr = w * 32 + (lane >> 2);      // staging row
    const int sc = (lane & 3) * 8;            // staging col (bf16 elems)

    f32x4 acc[4][4] = {};

    for (int k0 = 0; k0 < K; k0 += 32) {
        const __bf16* ga = A  + (size_t)(bm + sr) * K + k0 + sc;
        const __bf16* gb = BT + (size_t)(bn + sr) * K + k0 + sc;
        load_lds16(ga,                 &As[(w * 32) * 32]);
        load_lds16(ga + (size_t)16 * K, &As[(w * 32 + 16) * 32]);
        load_lds16(gb,                 &Bs[(w * 32) * 32]);
        load_lds16(gb + (size_t)16 * K, &Bs[(w * 32 + 16) * 32]);
        __syncthreads();

        bf16x8 af[4], bfr[4];
        #pragma unroll
        for (int mi = 0; mi < 4; ++mi)
            af[mi] = *(bf16x8*)&As[(wm + mi * 16 + lc) * 32 + quad * 8];
        #pragma unroll
        for (int ni = 0; ni < 4; ++ni)
            bfr[ni] = *(bf16x8*)&Bs[(wn + ni * 16 + lc) * 32 + quad * 8];
        #pragma unroll
        for (int mi = 0; mi < 4; ++mi)
            #pragma unroll
            for (int ni = 0; ni < 4; ++ni)
                acc[mi][ni] = __builtin_amdgcn_mfma_f32_16x16x32_bf16(
                    af[mi], bfr[ni], acc[mi][ni], 0, 0, 0);
        __syncthreads();
    }

    // C/D layout: col = lane&15, row = quad*4 + r
    #pragma unroll
    for (int mi = 0; mi < 4; ++mi)
        #pragma unroll
        for (int r = 0; r < 4; ++r) {
            const size_t base =
                (size_t)(bm + wm + mi * 16 + quad * 4 + r) * N + bn + wn + lc;
            #pragma unroll
            for (int ni = 0; ni < 4; ++ni) {
                float v = acc[mi][ni][r];
                if constexpr (WF32)  Cf[base + ni * 16] = v;
                if constexpr (WBF16) Cb[base + ni * 16] = (__bf16)v;
            }
        }
}

// ============ fp32 tiled GEMM (kept for the two N=64 GEMMs) ================
__global__ __launch_bounds__(256)
void gemm_f32(const float* __restrict__ A, const float* __restrict__ B,
              float* __restrict__ C, int M, int N, int K) {
    __shared__ float As[16][68];
    __shared__ float Bs[16][68];
    const int bm = blockIdx.y * 64;
    const int bn = blockIdx.x * 64;
    const int tid = threadIdx.x;
    const int tm  = (tid >> 4) << 2;
    const int tn  = (tid & 15) << 2;
    const int lar = tid >> 2;
    const int lac = (tid & 3) << 2;
    const int lbr = tid >> 4;
    const int lbc = (tid & 15) << 2;

    float acc[4][4] = {{0.f,0.f,0.f,0.f},{0.f,0.f,0.f,0.f},
                       {0.f,0.f,0.f,0.f},{0.f,0.f,0.f,0.f}};

    for (int k0 = 0; k0 < K; k0 += 16) {
        float4 a = *(const float4*)(A + (size_t)(bm + lar) * K + (k0 + lac));
        As[lac + 0][lar] = a.x;
        As[lac + 1][lar] = a.y;
        As[lac + 2][lar] = a.z;
        As[lac + 3][lar] = a.w;
        *(float4*)&Bs[lbr][lbc] =
            *(const float4*)(B + (size_t)(k0 + lbr) * N + (bn + lbc));
        __syncthreads();
        #pragma unroll
        for (int k = 0; k < 16; ++k) {
            float4 a4 = *(float4*)&As[k][tm];
            float4 b4 = *(float4*)&Bs[k][tn];
            float av[4] = {a4.x, a4.y, a4.z, a4.w};
            float bv[4] = {b4.x, b4.y, b4.z, b4.w};
            #pragma unroll
            for (int i = 0; i < 4; ++i)
                #pragma unroll
                for (int j = 0; j < 4; ++j)
                    acc[i][j] += av[i] * bv[j];
        }
        __syncthreads();
    }
    #pragma unroll
    for (int i = 0; i < 4; ++i) {
        float4 o = make_float4(acc[i][0], acc[i][1], acc[i][2], acc[i][3]);
        *(float4*)(C + (size_t)(bm + tm + i) * N + (bn + tn)) = o;
    }
}

// ============ RoPE in place on (ROWS, 64) fp32 =============================
__global__ void rope_kernel(float* __restrict__ p) {
    int idx = blockIdx.x * blockDim.x + threadIdx.x;
    if (idx >= ROWS * 32) return;
    int row = idx >> 5;
    int i   = idx & 31;
    int t   = row & (Tt - 1);
    float inv  = powf(10000.0f, -(float)(2 * i) / 64.0f);
    float freq = (float)t * inv;
    float c = cosf(freq), s = sinf(freq);
    float* v = p + (size_t)row * DR;
    float x1 = v[i], x2 = v[i + 32];
    v[i]      = x1 * c - x2 * s;
    v[i + 32] = x2 * c + x1 * s;
}

// ============ fp32 -> bf16 convert =========================================
__global__ void f32_to_bf16(const float* __restrict__ in,
                            __bf16* __restrict__ out, int n) {
    int i = blockIdx.x * blockDim.x + threadIdx.x;
    if (i < n) out[i] = (__bf16)in[i];
}

// ============ transpose + convert: W[R][C] f32 -> WT[C][R] bf16 ============
__global__ __launch_bounds__(256)
void transpose_conv(const float* __restrict__ W, __bf16* __restrict__ WT,
                    int R, int C) {
    __shared__ float tile[64][65];
    const int r0 = blockIdx.x * 64;
    const int c0 = blockIdx.y * 64;
    const int tid = threadIdx.x;
    for (int e = tid; e < 64 * 64; e += 256) {
        int i = e >> 6, j = e & 63;
        tile[i][j] = W[(size_t)(r0 + i) * C + c0 + j];
    }
    __syncthreads();
    for (int e = tid; e < 64 * 64; e += 256) {
        int i = e >> 6, j = e & 63;
        WT[(size_t)(c0 + i) * R + r0 + j] = (__bf16)tile[j][i];
    }
}

// ============ entry = concat([ckv, kr_roped], -1) -> (ROWS, 576) ===========
__global__ void entry_kernel(const float* __restrict__ ckv,
                             const float* __restrict__ kr,
                             float* __restrict__ ent) {
    int idx = blockIdx.x * blockDim.x + threadIdx.x;
    if (idx >= ROWS * (DC + DR)) return;
    int row = idx / (DC + DR);
    int c   = idx % (DC + DR);
    ent[idx] = (c < DC) ? ckv[(size_t)row * DC + c]
                        : kr[(size_t)row * DR + (c - DC)];
}

// ============ V transpose: vb[B][T][D] -> vtb[B][D][T] (bf16) ==============
__global__ __launch_bounds__(256)
void transpose_v(const __bf16* __restrict__ vb, __bf16* __restrict__ vtb) {
    __shared__ __bf16 tile[64][65];
    const int t0 = blockIdx.x * 64;
    const int c0 = blockIdx.y * 64;
    const int b  = blockIdx.z;
    const int tid = threadIdx.x;
    for (int e = tid; e < 64 * 64; e += 256) {
        int i = e >> 6, j = e & 63;
        tile[i][j] = vb[((size_t)(b * Tt + t0 + i)) * D + c0 + j];
    }
    __syncthreads();
    for (int e = tid; e < 64 * 64; e += 256) {
        int i = e >> 6, j = e & 63;
        vtb[((size_t)(b * D + c0 + i)) * Tt + t0 + j] = tile[j][i];
    }
}

// ============ MFMA flash attention (bf16 out) ==============================
#define QS_STR 200
#define VT_STR 72
#define PS_STR 72

__global__ __launch_bounds__(256)
void attn_mfma(const __bf16* __restrict__ qb, const __bf16* __restrict__ kb,
               const __bf16* __restrict__ vtb, const __bf16* __restrict__ qrb,
               const __bf16* __restrict__ krb, __bf16* __restrict__ out) {
    __shared__ __bf16 Qs[64][QS_STR];
    __shared__ __bf16 Ks[64][QS_STR];
    __shared__ __bf16 Vt[128][VT_STR];
    __shared__ __bf16 Ps[4][16][PS_STR];

    const int tid  = threadIdx.x;
    const int w    = tid >> 6;
    const int lane = tid & 63;
    const int quad = lane >> 4;
    const int lc   = lane & 15;
    const int q0   = blockIdx.x * 64;
    const int h    = blockIdx.y;
    const int b    = blockIdx.z;

    {
        const __bf16* qbase = qb + ((size_t)(b * Tt + q0)) * D + h * HD;
        for (int c = tid; c < 64 * 16; c += 256) {
            int row = c >> 4, c8 = c & 15;
            *(bf16x8*)&Qs[row][c8 * 8] =
                *(const bf16x8*)(qbase + (size_t)row * D + c8 * 8);
        }
        const __bf16* qrbase = qrb + ((size_t)(b * Tt + q0)) * DR;
        for (int c = tid; c < 64 * 8; c += 256) {
            int row = c >> 3, c8 = c & 7;
            *(bf16x8*)&Qs[row][128 + c8 * 8] =
                *(const bf16x8*)(qrbase + (size_t)row * DR + c8 * 8);
        }
    }

    float m_i[4], l_i[4];
    f32x4 Of[8];
    #pragma unroll
    for (int r = 0; r < 4; ++r) { m_i[r] = -1e30f; l_i[r] = 0.f; }
    #pragma unroll
    for (int n = 0; n < 8; ++n) Of[n] = (f32x4){0.f, 0.f, 0.f, 0.f};

    const int ntiles = blockIdx.x + 1;
    const float rscale = 0.07216878364870323f;   // 1/sqrt(192)
    const int qrow = q0 + w * 16 + quad * 4;

    for (int it = 0; it < ntiles; ++it) {
        const int s0 = it * 64;
        __syncthreads();
        const __bf16* kbase = kb + ((size_t)(b * Tt + s0)) * D + h * HD;
        for (int c = tid; c < 64 * 16; c += 256) {
            int row = c >> 4, c8 = c & 15;
            *(bf16x8*)&Ks[row][c8 * 8] =
                *(const bf16x8*)(kbase + (size_t)row * D + c8 * 8);
        }
        const __bf16* krbase = krb + ((size_t)(b * Tt + s0)) * DR;
        for (int c = tid; c < 64 * 8; c += 256) {
            int row = c >> 3, c8 = c & 7;
            *(bf16x8*)&Ks[row][128 + c8 * 8] =
                *(const bf16x8*)(krbase + (size_t)row * DR + c8 * 8);
        }
        const __bf16* vbase = vtb + ((size_t)(b * D + h * HD)) * Tt + s0;
        for (int c = tid; c < 128 * 8; c += 256) {
            int n = c >> 3, c8 = c & 7;
            *(bf16x8*)&Vt[n][c8 * 8] =
                *(const bf16x8*)(vbase + (size_t)n * Tt + c8 * 8);
        }
        __syncthreads();

        f32x4 sc[4];
        #pragma unroll
        for (int f = 0; f < 4; ++f) sc[f] = (f32x4){0.f, 0.f, 0.f, 0.f};
        #pragma unroll
        for (int kt = 0; kt < 6; ++kt) {
            bf16x8 aq = *(bf16x8*)&Qs[w * 16 + lc][kt * 32 + quad * 8];
            #pragma unroll
            for (int f = 0; f < 4; ++f) {
                bf16x8 bk = *(bf16x8*)&Ks[f * 16 + lc][kt * 32 + quad * 8];
                sc[f] = __builtin_amdgcn_mfma_f32_16x16x32_bf16(aq, bk, sc[f], 0, 0, 0);
            }
        }

        float pv[4][4], mt[4];
        #pragma unroll
        for (int r = 0; r < 4; ++r) mt[r] = -1e30f;
        const bool need_mask = (s0 == q0);
        #pragma unroll
        for (int f = 0; f < 4; ++f) {
            #pragma unroll
            for (int r = 0; r < 4; ++r) {
                float sv = sc[f][r] * rscale;
                if (need_mask && (s0 + f * 16 + lc > qrow + r)) sv = -1e30f;
                pv[f][r] = sv;
                mt[r] = fmaxf(mt[r], sv);
            }
        }
        #pragma unroll
        for (int off = 1; off < 16; off <<= 1)
            #pragma unroll
            for (int r = 0; r < 4; ++r)
                mt[r] = fmaxf(mt[r], __shfl_xor(mt[r], off, 64));
        float alpha[4], rs[4];
        #pragma unroll
        for (int r = 0; r < 4; ++r) {
            float mn = fmaxf(m_i[r], mt[r]);
            alpha[r] = __expf(m_i[r] - mn);
            m_i[r] = mn;
            rs[r] = 0.f;
        }
        #pragma unroll
        for (int f = 0; f < 4; ++f) {
            #pragma unroll
            for (int r = 0; r < 4; ++r) {
                __bf16 pb = (__bf16)__expf(pv[f][r] - m_i[r]);
                Ps[w][quad * 4 + r][f * 16 + lc] = pb;
                rs[r] += (float)pb;
            }
        }
        #pragma unroll
        for (int off = 1; off < 16; off <<= 1)
            #pragma unroll
            for (int r = 0; r < 4; ++r)
                rs[r] += __shfl_xor(rs[r], off, 64);
        #pragma unroll
        for (int r = 0; r < 4; ++r) l_i[r] = l_i[r] * alpha[r] + rs[r];
        #pragma unroll
        for (int n = 0; n < 8; ++n)
            #pragma unroll
            for (int r = 0; r < 4; ++r) Of[n][r] *= alpha[r];

        __syncthreads();

        #pragma unroll
        for (int kt = 0; kt < 2; ++kt) {
            bf16x8 ap = *(bf16x8*)&Ps[w][lc][kt * 32 + quad * 8];
            #pragma unroll
            for (int n = 0; n < 8; ++n) {
                bf16x8 bv = *(bf16x8*)&Vt[n * 16 + lc][kt * 32 + quad * 8];
                Of[n] = __builtin_amdgcn_mfma_f32_16x16x32_bf16(ap, bv, Of[n], 0, 0, 0);
            }
        }
    }

    __bf16* obase = out + ((size_t)(b * Tt + q0 + w * 16 + quad * 4)) * D + h * HD + lc;
    #pragma unroll
    for (int r = 0; r < 4; ++r) {
        float inv = 1.0f / l_i[r];
        #pragma unroll
        for (int n = 0; n < 8; ++n)
            obase[(size_t)r * D + n * 16] = (__bf16)(Of[n][r] * inv);
    }
}

extern "C" void kernel_launch(void* const* d_in, const int* in_sizes, int n_in,
                              void* d_out, int out_size, void* d_ws, size_t ws_size,
                              hipStream_t stream) {
    const float* x    = (const float*)d_in[0];
    const float* Wkv  = (const float*)d_in[1];
    const float* Wkup = (const float*)d_in[2];
    const float* Wvup = (const float*)d_in[3];
    const float* Wq   = (const float*)d_in[4];
    const float* Wqr  = (const float*)d_in[5];
    const float* Wkr  = (const float*)d_in[6];
    const float* Wo   = (const float*)d_in[7];

    float* out0 = (float*)d_out;                     // (4096, 2048)
    float* out1 = out0 + (size_t)ROWS * D;           // (4096, 576) entry

    char* wsb = (char*)d_ws;
    float*  ckv   = (float*)wsb;   wsb += (size_t)ROWS * DC * 4;   //  8 MB
    float*  krf   = (float*)wsb;   wsb += (size_t)ROWS * DR * 4;   //  1 MB
    float*  qrf   = (float*)wsb;   wsb += (size_t)ROWS * DR * 4;   //  1 MB
    __bf16* xb    = (__bf16*)wsb;  wsb += (size_t)ROWS * D  * 2;   // 16.8 MB
    __bf16* ckvb  = (__bf16*)wsb;  wsb += (size_t)ROWS * DC * 2;   //  4.2 MB
    __bf16* qb    = (__bf16*)wsb;  wsb += (size_t)ROWS * D  * 2;
    __bf16* kb    = (__bf16*)wsb;  wsb += (size_t)ROWS * D  * 2;
    __bf16* vb    = (__bf16*)wsb;  wsb += (size_t)ROWS * D  * 2;
    __bf16* vtb   = (__bf16*)wsb;  wsb += (size_t)ROWS * D  * 2;
    __bf16* aob   = (__bf16*)wsb;  wsb += (size_t)ROWS * D  * 2;
    __bf16* qrb   = (__bf16*)wsb;  wsb += (size_t)ROWS * DR * 2;
    __bf16* krb   = (__bf16*)wsb;  wsb += (size_t)ROWS * DR * 2;
    __bf16* WkvT  = (__bf16*)wsb;  wsb += (size_t)D  * DC * 2;     //  2 MB
    __bf16* WkupT = (__bf16*)wsb;  wsb += (size_t)DC * D  * 2;     //  2 MB
    __bf16* WvupT = (__bf16*)wsb;  wsb += (size_t)DC * D  * 2;     //  2 MB
    __bf16* WqT   = (__bf16*)wsb;  wsb += (size_t)D  * D  * 2;     //  8 MB
    __bf16* WoT   = (__bf16*)wsb;  wsb += (size_t)D  * D  * 2;     //  8 MB

    dim3 blk(256);

    // --- precision staging: converts + weight transposes ---
    f32_to_bf16<<<(ROWS * D + 255) / 256, blk, 0, stream>>>(x, xb, ROWS * D);
    transpose_conv<<<dim3(D / 64, DC / 64),  blk, 0, stream>>>(Wkv,  WkvT,  D,  DC);
    transpose_conv<<<dim3(DC / 64, D / 64),  blk, 0, stream>>>(Wkup, WkupT, DC, D);
    transpose_conv<<<dim3(DC / 64, D / 64),  blk, 0, stream>>>(Wvup, WvupT, DC, D);
    transpose_conv<<<dim3(D / 64, D / 64),   blk, 0, stream>>>(Wq,   WqT,   D,  D);
    transpose_conv<<<dim3(D / 64, D / 64),   blk, 0, stream>>>(Wo,   WoT,   D,  D);

    // --- ckv = x @ Wkv  (fp32 + bf16 outputs) ---
    gemm_bt<true, true><<<dim3(DC / 128, ROWS / 128), blk, 0, stream>>>(
        xb, WkvT, ckv, ckvb, ROWS, DC, D);

    // --- kr = rope(ckv @ Wkr); entry output ---
    gemm_f32<<<dim3(DR / 64, ROWS / 64), blk, 0, stream>>>(ckv, Wkr, krf, ROWS, DR, DC);
    rope_kernel<<<(ROWS * 32 + 255) / 256, blk, 0, stream>>>(krf);
    f32_to_bf16<<<(ROWS * DR + 255) / 256, blk, 0, stream>>>(krf, krb, ROWS * DR);
    entry_kernel<<<(ROWS * (DC + DR) + 255) / 256, blk, 0, stream>>>(ckv, krf, out1);

    // --- q, qr ---
    gemm_bt<false, true><<<dim3(D / 128, ROWS / 128), blk, 0, stream>>>(
        xb, WqT, (float*)nullptr, qb, ROWS, D, D);
    gemm_f32<<<dim3(DR / 64, ROWS / 64), blk, 0, stream>>>(x, Wqr, qrf, ROWS, DR, D);
    rope_kernel<<<(ROWS * 32 + 255) / 256, blk, 0, stream>>>(qrf);
    f32_to_bf16<<<(ROWS * DR + 255) / 256, blk, 0, stream>>>(qrf, qrb, ROWS * DR);

    // --- k, v up-projections; v transpose ---
    gemm_bt<false, true><<<dim3(D / 128, ROWS / 128), blk, 0, stream>>>(
        ckvb, WkupT, (float*)nullptr, kb, ROWS, D, DC);
    gemm_bt<false, true><<<dim3(D / 128, ROWS / 128), blk, 0, stream>>>(
        ckvb, WvupT, (float*)nullptr, vb, ROWS, D, DC);
    transpose_v<<<dim3(Tt / 64, D / 64, Bb), blk, 0, stream>>>(vb, vtb);

    // --- attention (bf16 out) ---
    attn_mfma<<<dim3(Tt / 64, NH, Bb), blk, 0, stream>>>(qb, kb, vtb, qrb, krb, aob);

    // --- out0 = ao @ Wo ---
    gemm_bt<true, false><<<dim3(D / 128, ROWS / 128), blk, 0, stream>>>(
        aob, WoT, out0, (__bf16*)nullptr, ROWS, D, D);
}

// Round 4
// 600.082 us; speedup vs baseline: 10.3642x; 1.4280x over previous
//
#include <hip/hip_runtime.h>
#include <math.h>
#include <type_traits>

#define D    2048
#define DC   512
#define DR   64
#define NH   16
#define HD   128
#define Bb   2
#define Tt   2048
#define ROWS (Bb*Tt)   // 4096
#define LDX  2176      // row stride of q_ext / k_ext (2048 + 64 + 64 pad)

typedef __bf16 bf16x8 __attribute__((ext_vector_type(8)));
typedef float  f32x4  __attribute__((ext_vector_type(4)));

typedef const void __attribute__((address_space(1))) gvoid;
typedef void       __attribute__((address_space(3))) lvoid;

__device__ __forceinline__ void load_lds16(const void* g, void* l) {
    __builtin_amdgcn_global_load_lds((gvoid*)g, (lvoid*)l, 16, 0, 0);
}

// ============ bf16 MFMA GEMM: C = A[M,K] @ BT[N,K]^T, ldc variants =========
// 128x128 tile, BK=32, 4 waves, 4x4 16x16x32 accs, global_load_lds staging.
template <bool WF32, bool WBF16>
__global__ __launch_bounds__(256)
void gemm_bt(const __bf16* __restrict__ A, const __bf16* __restrict__ BT,
             float* __restrict__ Cf, __bf16* __restrict__ Cb,
             int M, int K, int ldcf, int ldcb) {
    __shared__ __bf16 As[128 * 32];
    __shared__ __bf16 Bs[128 * 32];

    const int tid  = threadIdx.x;
    const int w    = tid >> 6;
    const int lane = tid & 63;
    const int quad = lane >> 4;
    const int lc   = lane & 15;
    const int bm   = blockIdx.y * 128;
    const int bn   = blockIdx.x * 128;
    const int wm   = (w & 1) * 64;
    const int wn   = (w >> 1) * 64;

    const int sr = w * 32 + (lane >> 2);
    const int sc = (lane & 3) * 8;

    f32x4 acc[4][4] = {};

    for (int k0 = 0; k0 < K; k0 += 32) {
        const __bf16* ga = A  + (size_t)(bm + sr) * K + k0 + sc;
        const __bf16* gb = BT + (size_t)(bn + sr) * K + k0 + sc;
        load_lds16(ga,                  &As[(w * 32) * 32]);
        load_lds16(ga + (size_t)16 * K, &As[(w * 32 + 16) * 32]);
        load_lds16(gb,                  &Bs[(w * 32) * 32]);
        load_lds16(gb + (size_t)16 * K, &Bs[(w * 32 + 16) * 32]);
        __syncthreads();

        bf16x8 af[4], bfr[4];
        #pragma unroll
        for (int mi = 0; mi < 4; ++mi)
            af[mi] = *(bf16x8*)&As[(wm + mi * 16 + lc) * 32 + quad * 8];
        #pragma unroll
        for (int ni = 0; ni < 4; ++ni)
            bfr[ni] = *(bf16x8*)&Bs[(wn + ni * 16 + lc) * 32 + quad * 8];
        #pragma unroll
        for (int mi = 0; mi < 4; ++mi)
            #pragma unroll
            for (int ni = 0; ni < 4; ++ni)
                acc[mi][ni] = __builtin_amdgcn_mfma_f32_16x16x32_bf16(
                    af[mi], bfr[ni], acc[mi][ni], 0, 0, 0);
        __syncthreads();
    }

    #pragma unroll
    for (int mi = 0; mi < 4; ++mi)
        #pragma unroll
        for (int r = 0; r < 4; ++r) {
            const int row = bm + wm + mi * 16 + quad * 4 + r;
            const int col = bn + wn + lc;
            #pragma unroll
            for (int ni = 0; ni < 4; ++ni) {
                float v = acc[mi][ni][r];
                if constexpr (WF32)  Cf[(size_t)row * ldcf + col + ni * 16] = v;
                if constexpr (WBF16) Cb[(size_t)row * ldcb + col + ni * 16] = (__bf16)v;
            }
        }
}

// ============ fp32 -> bf16 convert =========================================
__global__ void f32_to_bf16(const float* __restrict__ in,
                            __bf16* __restrict__ out, int n) {
    int i = blockIdx.x * blockDim.x + threadIdx.x;
    if (i < n) out[i] = (__bf16)in[i];
}

// ============ transpose + convert: W[R][C] f32 -> WT[C][R] bf16 ============
__global__ __launch_bounds__(256)
void transpose_conv(const float* __restrict__ W, __bf16* __restrict__ WT,
                    int R, int C) {
    __shared__ float tile[64][65];
    const int r0 = blockIdx.x * 64;
    const int c0 = blockIdx.y * 64;
    const int tid = threadIdx.x;
    for (int e = tid; e < 64 * 64; e += 256) {
        int i = e >> 6, j = e & 63;
        tile[i][j] = W[(size_t)(r0 + i) * C + c0 + j];
    }
    __syncthreads();
    for (int e = tid; e < 64 * 64; e += 256) {
        int i = e >> 6, j = e & 63;
        WT[(size_t)(c0 + i) * R + r0 + j] = (__bf16)tile[j][i];
    }
}

// ============ RoPE in-place on ext-buffer cols 2048..2111 (bf16) ===========
// If ent != nullptr, also writes fp32 roped values into entry cols 512..575.
__global__ void rope_ext(__bf16* __restrict__ p, float* __restrict__ ent) {
    int idx = blockIdx.x * blockDim.x + threadIdx.x;
    if (idx >= ROWS * 32) return;
    int row = idx >> 5;
    int i   = idx & 31;
    int t   = row & (Tt - 1);
    float inv  = powf(10000.0f, -(float)(2 * i) / 64.0f);
    float fr   = (float)t * inv;
    float c = cosf(fr), s = sinf(fr);
    __bf16* v = p + (size_t)row * LDX + 2048;
    float x1 = (float)v[i], x2 = (float)v[i + 32];
    float o1 = x1 * c - x2 * s;
    float o2 = x2 * c + x1 * s;
    v[i]      = (__bf16)o1;
    v[i + 32] = (__bf16)o2;
    if (ent) {
        ent[(size_t)row * 576 + 512 + i] = o1;
        ent[(size_t)row * 576 + 544 + i] = o2;
    }
}

// ============ V transpose: vb[B][T][D] -> vtb[B][D][T] (bf16) ==============
__global__ __launch_bounds__(256)
void transpose_v(const __bf16* __restrict__ vb, __bf16* __restrict__ vtb) {
    __shared__ __bf16 tile[64][65];
    const int t0 = blockIdx.x * 64;
    const int c0 = blockIdx.y * 64;
    const int b  = blockIdx.z;
    const int tid = threadIdx.x;
    for (int e = tid; e < 64 * 64; e += 256) {
        int i = e >> 6, j = e & 63;
        tile[i][j] = vb[((size_t)(b * Tt + t0 + i)) * D + c0 + j];
    }
    __syncthreads();
    for (int e = tid; e < 64 * 64; e += 256) {
        int i = e >> 6, j = e & 63;
        vtb[((size_t)(b * D + c0 + i)) * Tt + t0 + j] = tile[j][i];
    }
}

// ============ MFMA flash attention v2 ======================================
// qx,kx: (B,T,LDX) bf16 ext buffers (head h at h*HD, rope at 2048..2111).
// vtb: (B,D,T) bf16. Q in registers; K/V register-double-buffered staging.
#define KS_STR 200
#define VT_STR 72
#define PS_STR 72

__global__ __launch_bounds__(256, 3)
void attn_mfma(const __bf16* __restrict__ qx, const __bf16* __restrict__ kx,
               const __bf16* __restrict__ vtb, __bf16* __restrict__ out) {
    __shared__ __bf16 Ks[64][KS_STR];      // 25.6 KB (cols 0..127 k, 128..191 kr)
    __shared__ __bf16 Vt[128][VT_STR];     // 18.4 KB
    __shared__ __bf16 Ps[4][16][PS_STR];   //  9.2 KB  (total ~53 KB: 3 blocks/CU)

    const int tid  = threadIdx.x;
    const int w    = tid >> 6;
    const int lane = tid & 63;
    const int quad = lane >> 4;
    const int lc   = lane & 15;
    const int qt   = (int)gridDim.x - 1 - (int)blockIdx.x;  // longest first
    const int q0   = qt * 64;
    const int h    = blockIdx.y;
    const int b    = blockIdx.z;

    // ---- Q fragments in registers (wave w owns q rows q0+w*16..+15) ----
    bf16x8 aq[6];
    {
        const __bf16* qrow = qx + (size_t)(b * Tt + q0 + w * 16 + lc) * LDX;
        #pragma unroll
        for (int kt = 0; kt < 4; ++kt)
            aq[kt] = *(const bf16x8*)(qrow + h * HD + kt * 32 + quad * 8);
        #pragma unroll
        for (int kt = 0; kt < 2; ++kt)
            aq[4 + kt] = *(const bf16x8*)(qrow + 2048 + kt * 32 + quad * 8);
    }

    // ---- staging geometry ----
    int krow[6], kcol[6], kgo[6];
    #pragma unroll
    for (int j = 0; j < 6; ++j) {
        int c   = tid + j * 256;       // 0..1535 over 64 rows x 24 chunks
        int row = c / 24, c24 = c - row * 24;
        krow[j] = row;
        kcol[j] = c24 * 8;
        kgo[j]  = row * LDX + ((c24 < 16) ? (h * HD + c24 * 8)
                                          : (2048 + (c24 - 16) * 8));
    }
    const int vrow = tid >> 3;           // + j*32
    const int vcol = (tid & 7) * 8;
    const __bf16* kb0 = kx + (size_t)b * Tt * LDX;
    const __bf16* vb0 = vtb + ((size_t)b * D + (size_t)h * HD) * Tt;

    bf16x8 pk[6], pvv[4];
    #pragma unroll
    for (int j = 0; j < 6; ++j) pk[j] = *(const bf16x8*)(kb0 + kgo[j]);
    #pragma unroll
    for (int j = 0; j < 4; ++j)
        pvv[j] = *(const bf16x8*)(vb0 + (vrow + j * 32) * Tt + vcol);

    float m_i[4], l_i[4];
    f32x4 Of[8];
    #pragma unroll
    for (int r = 0; r < 4; ++r) { m_i[r] = -1e30f; l_i[r] = 0.f; }
    #pragma unroll
    for (int n = 0; n < 8; ++n) Of[n] = (f32x4){0.f, 0.f, 0.f, 0.f};

    const float rscale = 0.07216878364870323f;   // 1/sqrt(192)
    const int qrow_g = q0 + w * 16 + quad * 4;

    for (int it = 0; it <= qt; ++it) {
        const int s0 = it * 64;
        __syncthreads();                       // LDS free (prev PV done)
        #pragma unroll
        for (int j = 0; j < 6; ++j) *(bf16x8*)&Ks[krow[j]][kcol[j]] = pk[j];
        #pragma unroll
        for (int j = 0; j < 4; ++j) *(bf16x8*)&Vt[vrow + j * 32][vcol] = pvv[j];
        __syncthreads();

        if (it < qt) {                          // prefetch next tile -> regs
            const __bf16* kbn = kb0 + (size_t)(s0 + 64) * LDX;
            const __bf16* vbn = vb0 + (s0 + 64);
            #pragma unroll
            for (int j = 0; j < 6; ++j) pk[j] = *(const bf16x8*)(kbn + kgo[j]);
            #pragma unroll
            for (int j = 0; j < 4; ++j)
                pvv[j] = *(const bf16x8*)(vbn + (vrow + j * 32) * Tt + vcol);
        }

        // ---- S = Q K^T (K-dim 192 = 6 steps) ----
        f32x4 sc[4];
        #pragma unroll
        for (int f = 0; f < 4; ++f) sc[f] = (f32x4){0.f, 0.f, 0.f, 0.f};
        #pragma unroll
        for (int kt = 0; kt < 6; ++kt) {
            #pragma unroll
            for (int f = 0; f < 4; ++f) {
                bf16x8 bk = *(bf16x8*)&Ks[f * 16 + lc][kt * 32 + quad * 8];
                sc[f] = __builtin_amdgcn_mfma_f32_16x16x32_bf16(aq[kt], bk, sc[f], 0, 0, 0);
            }
        }

        // ---- online softmax (two passes over sc; no pv array) ----
        const bool need_mask = (it == qt);
        float mt[4];
        #pragma unroll
        for (int r = 0; r < 4; ++r) mt[r] = -1e30f;
        #pragma unroll
        for (int f = 0; f < 4; ++f)
            #pragma unroll
            for (int r = 0; r < 4; ++r) {
                float sv = sc[f][r] * rscale;
                if (need_mask && (s0 + f * 16 + lc > qrow_g + r)) sv = -1e30f;
                mt[r] = fmaxf(mt[r], sv);
            }
        #pragma unroll
        for (int off = 1; off < 16; off <<= 1)
            #pragma unroll
            for (int r = 0; r < 4; ++r)
                mt[r] = fmaxf(mt[r], __shfl_xor(mt[r], off, 64));
        float alpha[4], rs[4];
        #pragma unroll
        for (int r = 0; r < 4; ++r) {
            float mn = fmaxf(m_i[r], mt[r]);
            alpha[r] = __expf(m_i[r] - mn);
            m_i[r] = mn;
            rs[r] = 0.f;
        }
        #pragma unroll
        for (int f = 0; f < 4; ++f)
            #pragma unroll
            for (int r = 0; r < 4; ++r) {
                float sv = sc[f][r] * rscale;
                if (need_mask && (s0 + f * 16 + lc > qrow_g + r)) sv = -1e30f;
                __bf16 pb = (__bf16)__expf(sv - m_i[r]);
                Ps[w][quad * 4 + r][f * 16 + lc] = pb;
                rs[r] += (float)pb;
            }
        #pragma unroll
        for (int off = 1; off < 16; off <<= 1)
            #pragma unroll
            for (int r = 0; r < 4; ++r)
                rs[r] += __shfl_xor(rs[r], off, 64);
        #pragma unroll
        for (int r = 0; r < 4; ++r) l_i[r] = l_i[r] * alpha[r] + rs[r];
        #pragma unroll
        for (int n = 0; n < 8; ++n)
            #pragma unroll
            for (int r = 0; r < 4; ++r) Of[n][r] *= alpha[r];

        __syncthreads();                        // Ps visible to whole wave

        // ---- O += P V ----
        #pragma unroll
        for (int kt = 0; kt < 2; ++kt) {
            bf16x8 ap = *(bf16x8*)&Ps[w][lc][kt * 32 + quad * 8];
            #pragma unroll
            for (int n = 0; n < 8; ++n) {
                bf16x8 bv = *(bf16x8*)&Vt[n * 16 + lc][kt * 32 + quad * 8];
                Of[n] = __builtin_amdgcn_mfma_f32_16x16x32_bf16(ap, bv, Of[n], 0, 0, 0);
            }
        }
    }

    __bf16* obase = out + ((size_t)(b * Tt + qrow_g)) * D + h * HD + lc;
    #pragma unroll
    for (int r = 0; r < 4; ++r) {
        float inv = 1.0f / l_i[r];
        #pragma unroll
        for (int n = 0; n < 8; ++n)
            obase[(size_t)r * D + n * 16] = (__bf16)(Of[n][r] * inv);
    }
}

extern "C" void kernel_launch(void* const* d_in, const int* in_sizes, int n_in,
                              void* d_out, int out_size, void* d_ws, size_t ws_size,
                              hipStream_t stream) {
    const float* x    = (const float*)d_in[0];
    const float* Wkv  = (const float*)d_in[1];
    const float* Wkup = (const float*)d_in[2];
    const float* Wvup = (const float*)d_in[3];
    const float* Wq   = (const float*)d_in[4];
    const float* Wqr  = (const float*)d_in[5];
    const float* Wkr  = (const float*)d_in[6];
    const float* Wo   = (const float*)d_in[7];

    float* out0 = (float*)d_out;                     // (4096, 2048)
    float* out1 = out0 + (size_t)ROWS * D;           // (4096, 576) entry

    char* wsb = (char*)d_ws;
    __bf16* xb    = (__bf16*)wsb;  wsb += (size_t)ROWS * D   * 2;   // 16.8 MB
    __bf16* ckvb  = (__bf16*)wsb;  wsb += (size_t)ROWS * DC  * 2;   //  4.2 MB
    __bf16* qext  = (__bf16*)wsb;  wsb += (size_t)ROWS * LDX * 2;   // 17.8 MB
    __bf16* kext  = (__bf16*)wsb;  wsb += (size_t)ROWS * LDX * 2;   // 17.8 MB
    __bf16* vb    = (__bf16*)wsb;  wsb += (size_t)ROWS * D   * 2;   // 16.8 MB
    __bf16* vtb   = (__bf16*)wsb;  wsb += (size_t)ROWS * D   * 2;   // 16.8 MB
    __bf16* aob   = (__bf16*)wsb;  wsb += (size_t)ROWS * D   * 2;   // 16.8 MB
    __bf16* WkvT  = (__bf16*)wsb;  wsb += (size_t)D   * DC * 2;     //  2 MB
    __bf16* WqxT  = (__bf16*)wsb;  wsb += (size_t)LDX * D  * 2;     //  8.9 MB
    __bf16* KupxT = (__bf16*)wsb;  wsb += (size_t)LDX * DC * 2;     //  2.2 MB
    __bf16* WvupT = (__bf16*)wsb;  wsb += (size_t)DC  * D  * 2;     //  2 MB
    __bf16* WoT   = (__bf16*)wsb;  wsb += (size_t)D   * D  * 2;     //  8.4 MB

    dim3 blk(256);

    // --- staging: converts + weight transposes (qr/kr folded in) ---
    f32_to_bf16<<<(ROWS * D + 255) / 256, blk, 0, stream>>>(x, xb, ROWS * D);
    transpose_conv<<<dim3(D / 64, DC / 64), blk, 0, stream>>>(Wkv, WkvT, D, DC);
    transpose_conv<<<dim3(D / 64, D / 64),  blk, 0, stream>>>(Wq, WqxT, D, D);
    transpose_conv<<<dim3(D / 64, 1),       blk, 0, stream>>>(Wqr, WqxT + (size_t)D * D, D, DR);
    transpose_conv<<<dim3(DC / 64, D / 64), blk, 0, stream>>>(Wkup, KupxT, DC, D);
    transpose_conv<<<dim3(DC / 64, 1),      blk, 0, stream>>>(Wkr, KupxT + (size_t)D * DC, DC, DR);
    transpose_conv<<<dim3(DC / 64, D / 64), blk, 0, stream>>>(Wvup, WvupT, DC, D);
    transpose_conv<<<dim3(D / 64, D / 64),  blk, 0, stream>>>(Wo, WoT, D, D);

    // --- ckv = x @ Wkv: fp32 -> entry cols 0..511 (ldc 576), bf16 -> ckvb ---
    gemm_bt<true, true><<<dim3(DC / 128, ROWS / 128), blk, 0, stream>>>(
        xb, WkvT, out1, ckvb, ROWS, D, 576, DC);

    // --- q_ext = x @ [Wq | Wqr] (N=2176), then rope qr cols ---
    gemm_bt<false, true><<<dim3(LDX / 128, ROWS / 128), blk, 0, stream>>>(
        xb, WqxT, (float*)nullptr, qext, ROWS, D, 0, LDX);
    rope_ext<<<(ROWS * 32 + 255) / 256, blk, 0, stream>>>(qext, (float*)nullptr);

    // --- k_ext = ckv @ [Wkup | Wkr] (N=2176), rope kr cols + entry 512..575 ---
    gemm_bt<false, true><<<dim3(LDX / 128, ROWS / 128), blk, 0, stream>>>(
        ckvb, KupxT, (float*)nullptr, kext, ROWS, DC, 0, LDX);
    rope_ext<<<(ROWS * 32 + 255) / 256, blk, 0, stream>>>(kext, out1);

    // --- v = ckv @ Wvup; transpose ---
    gemm_bt<false, true><<<dim3(D / 128, ROWS / 128), blk, 0, stream>>>(
        ckvb, WvupT, (float*)nullptr, vb, ROWS, DC, 0, D);
    transpose_v<<<dim3(Tt / 64, D / 64, Bb), blk, 0, stream>>>(vb, vtb);

    // --- attention ---
    attn_mfma<<<dim3(Tt / 64, NH, Bb), blk, 0, stream>>>(qext, kext, vtb, aob);

    // --- out0 = ao @ Wo ---
    gemm_bt<true, false><<<dim3(D / 128, ROWS / 128), blk, 0, stream>>>(
        aob, WoT, out0, (__bf16*)nullptr, ROWS, D, D, 0);
}

// Round 5
// 552.641 us; speedup vs baseline: 11.2539x; 1.0858x over previous
//
#include <hip/hip_runtime.h>
#include <math.h>
#include <type_traits>

#define D    2048
#define DC   512
#define DR   64
#define NH   16
#define HD   128
#define Bb   2
#define Tt   2048
#define ROWS (Bb*Tt)   // 4096
#define LDX  2176      // row stride of q_ext / k_ext (2048 + 64 + 64 pad)

typedef __bf16 bf16x8 __attribute__((ext_vector_type(8)));
typedef __bf16 bf16x4 __attribute__((ext_vector_type(4)));
typedef float  f32x4  __attribute__((ext_vector_type(4)));

typedef const void __attribute__((address_space(1))) gvoid;
typedef void       __attribute__((address_space(3))) lvoid;

__device__ __forceinline__ void load_lds16(const void* g, void* l) {
    __builtin_amdgcn_global_load_lds((gvoid*)g, (lvoid*)l, 16, 0, 0);
}

// ============ bf16 MFMA GEMM: C = A[M,K] @ BT[N,K]^T, ldc variants =========
template <bool WF32, bool WBF16>
__global__ __launch_bounds__(256)
void gemm_bt(const __bf16* __restrict__ A, const __bf16* __restrict__ BT,
             float* __restrict__ Cf, __bf16* __restrict__ Cb,
             int M, int K, int ldcf, int ldcb) {
    __shared__ __bf16 As[128 * 32];
    __shared__ __bf16 Bs[128 * 32];

    const int tid  = threadIdx.x;
    const int w    = tid >> 6;
    const int lane = tid & 63;
    const int quad = lane >> 4;
    const int lc   = lane & 15;
    const int bm   = blockIdx.y * 128;
    const int bn   = blockIdx.x * 128;
    const int wm   = (w & 1) * 64;
    const int wn   = (w >> 1) * 64;

    const int sr = w * 32 + (lane >> 2);
    const int sc = (lane & 3) * 8;

    f32x4 acc[4][4] = {};

    for (int k0 = 0; k0 < K; k0 += 32) {
        const __bf16* ga = A  + (size_t)(bm + sr) * K + k0 + sc;
        const __bf16* gb = BT + (size_t)(bn + sr) * K + k0 + sc;
        load_lds16(ga,                  &As[(w * 32) * 32]);
        load_lds16(ga + (size_t)16 * K, &As[(w * 32 + 16) * 32]);
        load_lds16(gb,                  &Bs[(w * 32) * 32]);
        load_lds16(gb + (size_t)16 * K, &Bs[(w * 32 + 16) * 32]);
        __syncthreads();

        bf16x8 af[4], bfr[4];
        #pragma unroll
        for (int mi = 0; mi < 4; ++mi)
            af[mi] = *(bf16x8*)&As[(wm + mi * 16 + lc) * 32 + quad * 8];
        #pragma unroll
        for (int ni = 0; ni < 4; ++ni)
            bfr[ni] = *(bf16x8*)&Bs[(wn + ni * 16 + lc) * 32 + quad * 8];
        #pragma unroll
        for (int mi = 0; mi < 4; ++mi)
            #pragma unroll
            for (int ni = 0; ni < 4; ++ni)
                acc[mi][ni] = __builtin_amdgcn_mfma_f32_16x16x32_bf16(
                    af[mi], bfr[ni], acc[mi][ni], 0, 0, 0);
        __syncthreads();
    }

    #pragma unroll
    for (int mi = 0; mi < 4; ++mi)
        #pragma unroll
        for (int r = 0; r < 4; ++r) {
            const int row = bm + wm + mi * 16 + quad * 4 + r;
            const int col = bn + wn + lc;
            #pragma unroll
            for (int ni = 0; ni < 4; ++ni) {
                float v = acc[mi][ni][r];
                if constexpr (WF32)  Cf[(size_t)row * ldcf + col + ni * 16] = v;
                if constexpr (WBF16) Cb[(size_t)row * ldcb + col + ni * 16] = (__bf16)v;
            }
        }
}

// ============ fp32 -> bf16 convert =========================================
__global__ void f32_to_bf16(const float* __restrict__ in,
                            __bf16* __restrict__ out, int n) {
    int i = blockIdx.x * blockDim.x + threadIdx.x;
    if (i < n) out[i] = (__bf16)in[i];
}

// ============ transpose + convert: W[R][C] f32 -> WT[C][R] bf16 ============
__global__ __launch_bounds__(256)
void transpose_conv(const float* __restrict__ W, __bf16* __restrict__ WT,
                    int R, int C) {
    __shared__ float tile[64][65];
    const int r0 = blockIdx.x * 64;
    const int c0 = blockIdx.y * 64;
    const int tid = threadIdx.x;
    for (int e = tid; e < 64 * 64; e += 256) {
        int i = e >> 6, j = e & 63;
        tile[i][j] = W[(size_t)(r0 + i) * C + c0 + j];
    }
    __syncthreads();
    for (int e = tid; e < 64 * 64; e += 256) {
        int i = e >> 6, j = e & 63;
        WT[(size_t)(c0 + i) * R + r0 + j] = (__bf16)tile[j][i];
    }
}

// ============ RoPE in-place on ext-buffer cols 2048..2111 (bf16) ===========
__global__ void rope_ext(__bf16* __restrict__ p, float* __restrict__ ent) {
    int idx = blockIdx.x * blockDim.x + threadIdx.x;
    if (idx >= ROWS * 32) return;
    int row = idx >> 5;
    int i   = idx & 31;
    int t   = row & (Tt - 1);
    float inv  = powf(10000.0f, -(float)(2 * i) / 64.0f);
    float fr   = (float)t * inv;
    float c = cosf(fr), s = sinf(fr);
    __bf16* v = p + (size_t)row * LDX + 2048;
    float x1 = (float)v[i], x2 = (float)v[i + 32];
    float o1 = x1 * c - x2 * s;
    float o2 = x2 * c + x1 * s;
    v[i]      = (__bf16)o1;
    v[i + 32] = (__bf16)o2;
    if (ent) {
        ent[(size_t)row * 576 + 512 + i] = o1;
        ent[(size_t)row * 576 + 544 + i] = o2;
    }
}

// ============ V transpose: vb[B][T][D] -> vtb[B][D][T] (bf16) ==============
__global__ __launch_bounds__(256)
void transpose_v(const __bf16* __restrict__ vb, __bf16* __restrict__ vtb) {
    __shared__ __bf16 tile[64][65];
    const int t0 = blockIdx.x * 64;
    const int c0 = blockIdx.y * 64;
    const int b  = blockIdx.z;
    const int tid = threadIdx.x;
    for (int e = tid; e < 64 * 64; e += 256) {
        int i = e >> 6, j = e & 63;
        tile[i][j] = vb[((size_t)(b * Tt + t0 + i)) * D + c0 + j];
    }
    __syncthreads();
    for (int e = tid; e < 64 * 64; e += 256) {
        int i = e >> 6, j = e & 63;
        vtb[((size_t)(b * D + c0 + i)) * Tt + t0 + j] = tile[j][i];
    }
}

// ============ split-KV MFMA flash attention ================================
// Each block: one Q-tile (64 queries) x <=8 KV tiles (64 keys each).
// S^T = K.Q^T (lane owns ONE query -> 2-shuffle reduces, vectorized P^T),
// O^T = Vt.P^T. Partials (unnormalized O bf16, m/l fp32) -> reduce kernel.
#define KS_STR 200
#define VT_STR 72
#define PS_STR 72
#define SPLIT_TILES 8

// packed partial-slot base for a given qt (splits of 8 tiles)
__device__ __forceinline__ int pbase_qt(int qt) {
    int a = qt >> 3, r = qt & 7;
    return qt + 4 * a * (a - 1) + a * r;
}

__global__ __launch_bounds__(256, 3)
void attn_split(const __bf16* __restrict__ qx, const __bf16* __restrict__ kx,
                const __bf16* __restrict__ vtb, __bf16* __restrict__ opart,
                float* __restrict__ mlpart) {
    const int qt = (Tt / 64 - 1) - (int)blockIdx.y;   // longest-first
    const int sp = blockIdx.x;
    const int t0 = sp * SPLIT_TILES;
    if (t0 > qt) return;                               // unused split slot
    const int tend = min(t0 + SPLIT_TILES, qt + 1);
    const int hb = blockIdx.z;
    const int h  = hb & (NH - 1);
    const int b  = hb >> 4;
    const int q0 = qt * 64;

    __shared__ __bf16 Ks[64][KS_STR];       // 25.6 KB (k cols 0..127, kr 128..191)
    __shared__ __bf16 Vt[128][VT_STR];      // 18.4 KB
    __shared__ __bf16 PsT[4][16][PS_STR];   //  9.2 KB (wave-private P^T[query][key])

    const int tid  = threadIdx.x;
    const int w    = tid >> 6;
    const int lane = tid & 63;
    const int quad = lane >> 4;
    const int lc   = lane & 15;

    // ---- Q fragments (B-operand; same register layout as A) ----
    bf16x8 aq[6];
    {
        const __bf16* qrow = qx + (size_t)(b * Tt + q0 + w * 16 + lc) * LDX;
        #pragma unroll
        for (int kt = 0; kt < 4; ++kt)
            aq[kt] = *(const bf16x8*)(qrow + h * HD + kt * 32 + quad * 8);
        #pragma unroll
        for (int kt = 0; kt < 2; ++kt)
            aq[4 + kt] = *(const bf16x8*)(qrow + 2048 + kt * 32 + quad * 8);
    }

    // ---- staging geometry ----
    int krow[6], kcol[6], kgo[6];
    #pragma unroll
    for (int j = 0; j < 6; ++j) {
        int c   = tid + j * 256;
        int row = c / 24, c24 = c - row * 24;
        krow[j] = row;
        kcol[j] = c24 * 8;
        kgo[j]  = row * LDX + ((c24 < 16) ? (h * HD + c24 * 8)
                                          : (2048 + (c24 - 16) * 8));
    }
    const int vrow = tid >> 3;
    const int vcol = (tid & 7) * 8;
    const __bf16* kb0 = kx + (size_t)b * Tt * LDX;
    const __bf16* vb0 = vtb + ((size_t)b * D + (size_t)h * HD) * Tt;

    bf16x8 pk[6], pvv[4];
    {
        const __bf16* kbt = kb0 + (size_t)(t0 * 64) * LDX;
        const __bf16* vbt = vb0 + t0 * 64;
        #pragma unroll
        for (int j = 0; j < 6; ++j) pk[j] = *(const bf16x8*)(kbt + kgo[j]);
        #pragma unroll
        for (int j = 0; j < 4; ++j)
            pvv[j] = *(const bf16x8*)(vbt + (vrow + j * 32) * Tt + vcol);
    }

    float m_i = -1e30f, l_i = 0.f;     // per-lane: ONE query (lc)
    f32x4 Of[8];                        // O^T: hd = n*16+quad*4+r, query = lc
    #pragma unroll
    for (int n = 0; n < 8; ++n) Of[n] = (f32x4){0.f, 0.f, 0.f, 0.f};

    const float rscale = 0.07216878364870323f;   // 1/sqrt(192)
    const int qglob = q0 + w * 16 + lc;

    for (int it = t0; it < tend; ++it) {
        const int s0 = it * 64;
        __syncthreads();
        #pragma unroll
        for (int j = 0; j < 6; ++j) *(bf16x8*)&Ks[krow[j]][kcol[j]] = pk[j];
        #pragma unroll
        for (int j = 0; j < 4; ++j) *(bf16x8*)&Vt[vrow + j * 32][vcol] = pvv[j];
        __syncthreads();

        if (it + 1 < tend) {
            const __bf16* kbn = kb0 + (size_t)(s0 + 64) * LDX;
            const __bf16* vbn = vb0 + (s0 + 64);
            #pragma unroll
            for (int j = 0; j < 6; ++j) pk[j] = *(const bf16x8*)(kbn + kgo[j]);
            #pragma unroll
            for (int j = 0; j < 4; ++j)
                pvv[j] = *(const bf16x8*)(vbn + (vrow + j * 32) * Tt + vcol);
        }

        // ---- S^T = K Q^T : frag f holds keys f*16+quad*4+r, query lc ----
        f32x4 st[4];
        #pragma unroll
        for (int f = 0; f < 4; ++f) st[f] = (f32x4){0.f, 0.f, 0.f, 0.f};
        #pragma unroll
        for (int kt = 0; kt < 6; ++kt) {
            #pragma unroll
            for (int f = 0; f < 4; ++f) {
                bf16x8 ak = *(bf16x8*)&Ks[f * 16 + lc][kt * 32 + quad * 8];
                st[f] = __builtin_amdgcn_mfma_f32_16x16x32_bf16(ak, aq[kt], st[f], 0, 0, 0);
            }
        }

        // ---- softmax over keys (16 in-lane + 2 shuffles) ----
        const bool dm = (it == qt);
        float mt = -1e30f;
        #pragma unroll
        for (int f = 0; f < 4; ++f)
            #pragma unroll
            for (int r = 0; r < 4; ++r) {
                float sv = st[f][r] * rscale;
                if (dm && (s0 + f * 16 + quad * 4 + r > qglob)) sv = -1e30f;
                st[f][r] = sv;
                mt = fmaxf(mt, sv);
            }
        mt = fmaxf(mt, __shfl_xor(mt, 16, 64));
        mt = fmaxf(mt, __shfl_xor(mt, 32, 64));
        float mn = fmaxf(m_i, mt);
        float al = __expf(m_i - mn);
        m_i = mn;
        float rsum = 0.f;
        #pragma unroll
        for (int f = 0; f < 4; ++f) {
            bf16x4 pr;
            #pragma unroll
            for (int r = 0; r < 4; ++r) {
                __bf16 pb = (__bf16)__expf(st[f][r] - mn);
                pr[r] = pb;
                rsum += (float)pb;
            }
            *(bf16x4*)&PsT[w][lc][f * 16 + quad * 4] = pr;   // b64 vector write
        }
        rsum += __shfl_xor(rsum, 16, 64);
        rsum += __shfl_xor(rsum, 32, 64);
        l_i = l_i * al + rsum;
        #pragma unroll
        for (int n = 0; n < 8; ++n)
            #pragma unroll
            for (int r = 0; r < 4; ++r) Of[n][r] *= al;

        // ---- O^T += Vt P^T (wave-private PsT: no barrier needed) ----
        #pragma unroll
        for (int kt = 0; kt < 2; ++kt) {
            bf16x8 bp = *(bf16x8*)&PsT[w][lc][kt * 32 + quad * 8];
            #pragma unroll
            for (int n = 0; n < 8; ++n) {
                bf16x8 av = *(bf16x8*)&Vt[n * 16 + lc][kt * 32 + quad * 8];
                Of[n] = __builtin_amdgcn_mfma_f32_16x16x32_bf16(av, bp, Of[n], 0, 0, 0);
            }
        }
    }

    // ---- write partials ----
    const int p = hb * 80 + pbase_qt(qt) + sp;
    __bf16* ob = opart + (size_t)p * (64 * 128) + (size_t)(w * 16 + lc) * 128;
    #pragma unroll
    for (int n = 0; n < 8; ++n) {
        bf16x4 o4;
        #pragma unroll
        for (int r = 0; r < 4; ++r) o4[r] = (__bf16)Of[n][r];
        *(bf16x4*)(ob + n * 16 + quad * 4) = o4;
    }
    if (quad == 0) {
        mlpart[(size_t)p * 128 + w * 16 + lc]      = m_i;
        mlpart[(size_t)p * 128 + 64 + w * 16 + lc] = l_i;
    }
}

// ============ combine split partials -> aob (bf16) =========================
__global__ __launch_bounds__(256)
void attn_reduce(const __bf16* __restrict__ opart, const float* __restrict__ mlpart,
                 __bf16* __restrict__ aob) {
    const int qt = blockIdx.x;
    const int hb = blockIdx.y;
    const int h  = hb & (NH - 1);
    const int b  = hb >> 4;
    const int nsp = (qt >> 3) + 1;
    const int p0  = hb * 80 + pbase_qt(qt);
    const int tid = threadIdx.x;
    const int ql  = tid >> 2;
    const int cg  = (tid & 3) * 32;

    float M = -1e30f;
    for (int s = 0; s < nsp; ++s)
        M = fmaxf(M, mlpart[(size_t)(p0 + s) * 128 + ql]);
    float L = 0.f;
    float acc[32];
    #pragma unroll
    for (int j = 0; j < 32; ++j) acc[j] = 0.f;
    for (int s = 0; s < nsp; ++s) {
        float ms = mlpart[(size_t)(p0 + s) * 128 + ql];
        float ls = mlpart[(size_t)(p0 + s) * 128 + 64 + ql];
        float sc = __expf(ms - M);
        L += ls * sc;
        const __bf16* op = opart + (size_t)(p0 + s) * (64 * 128) + (size_t)ql * 128 + cg;
        #pragma unroll
        for (int j8 = 0; j8 < 4; ++j8) {
            bf16x8 v = *(const bf16x8*)(op + j8 * 8);
            #pragma unroll
            for (int e = 0; e < 8; ++e) acc[j8 * 8 + e] += sc * (float)v[e];
        }
    }
    float invL = 1.0f / L;
    __bf16* outp = aob + ((size_t)(b * Tt + qt * 64 + ql)) * D + h * HD + cg;
    #pragma unroll
    for (int j8 = 0; j8 < 4; ++j8) {
        bf16x8 v;
        #pragma unroll
        for (int e = 0; e < 8; ++e) v[e] = (__bf16)(acc[j8 * 8 + e] * invL);
        *(bf16x8*)(outp + j8 * 8) = v;
    }
}

extern "C" void kernel_launch(void* const* d_in, const int* in_sizes, int n_in,
                              void* d_out, int out_size, void* d_ws, size_t ws_size,
                              hipStream_t stream) {
    const float* x    = (const float*)d_in[0];
    const float* Wkv  = (const float*)d_in[1];
    const float* Wkup = (const float*)d_in[2];
    const float* Wvup = (const float*)d_in[3];
    const float* Wq   = (const float*)d_in[4];
    const float* Wqr  = (const float*)d_in[5];
    const float* Wkr  = (const float*)d_in[6];
    const float* Wo   = (const float*)d_in[7];

    float* out0 = (float*)d_out;                     // (4096, 2048)
    float* out1 = out0 + (size_t)ROWS * D;           // (4096, 576) entry

    // ---- persistent buffers ----
    char* wsb = (char*)d_ws;
    __bf16* qext = (__bf16*)wsb;  wsb += (size_t)ROWS * LDX * 2;   // 17.8 MB
    __bf16* kext = (__bf16*)wsb;  wsb += (size_t)ROWS * LDX * 2;   // 17.8 MB
    __bf16* vtb  = (__bf16*)wsb;  wsb += (size_t)ROWS * D   * 2;   // 16.8 MB
    __bf16* aob  = (__bf16*)wsb;  wsb += (size_t)ROWS * D   * 2;   // 16.8 MB
    __bf16* WoT  = (__bf16*)wsb;  wsb += (size_t)D * D * 2;        //  8.4 MB

    // ---- phase-1 scratch (dead before attention) / attention partials ----
    char* scratch = wsb;
    __bf16* xb    = (__bf16*)scratch;                        // 16.8 MB
    __bf16* vb    = (__bf16*)(scratch + 16777216);           // 16.8 MB
    __bf16* ckvb  = (__bf16*)(scratch + 33554432);           //  4.2 MB
    __bf16* WkvT  = (__bf16*)(scratch + 37748736);           //  2.1 MB
    __bf16* WqxT  = (__bf16*)(scratch + 39845888);           //  8.9 MB
    __bf16* KupxT = (__bf16*)(scratch + 48758784);           //  2.2 MB
    __bf16* WvupT = (__bf16*)(scratch + 50987008);           //  2.1 MB  (end 53.1 MB)
    // attention-phase aliases (overlay OK: all above dead by then)
    __bf16* opart  = (__bf16*)scratch;                       // 2560*16KB = 41.9 MB
    float*  mlpart = (float*)(scratch + (size_t)2560 * 64 * 128 * 2);  // 1.3 MB

    dim3 blk(256);

    // --- staging: converts + weight transposes (qr/kr folded in) ---
    f32_to_bf16<<<(ROWS * D + 255) / 256, blk, 0, stream>>>(x, xb, ROWS * D);
    transpose_conv<<<dim3(D / 64, DC / 64), blk, 0, stream>>>(Wkv, WkvT, D, DC);
    transpose_conv<<<dim3(D / 64, D / 64),  blk, 0, stream>>>(Wq, WqxT, D, D);
    transpose_conv<<<dim3(D / 64, 1),       blk, 0, stream>>>(Wqr, WqxT + (size_t)D * D, D, DR);
    transpose_conv<<<dim3(DC / 64, D / 64), blk, 0, stream>>>(Wkup, KupxT, DC, D);
    transpose_conv<<<dim3(DC / 64, 1),      blk, 0, stream>>>(Wkr, KupxT + (size_t)D * DC, DC, DR);
    transpose_conv<<<dim3(DC / 64, D / 64), blk, 0, stream>>>(Wvup, WvupT, DC, D);
    transpose_conv<<<dim3(D / 64, D / 64),  blk, 0, stream>>>(Wo, WoT, D, D);

    // --- ckv = x @ Wkv: fp32 -> entry cols 0..511 (ldc 576), bf16 -> ckvb ---
    gemm_bt<true, true><<<dim3(DC / 128, ROWS / 128), blk, 0, stream>>>(
        xb, WkvT, out1, ckvb, ROWS, D, 576, DC);

    // --- q_ext = x @ [Wq | Wqr] (N=2176), then rope qr cols ---
    gemm_bt<false, true><<<dim3(LDX / 128, ROWS / 128), blk, 0, stream>>>(
        xb, WqxT, (float*)nullptr, qext, ROWS, D, 0, LDX);
    rope_ext<<<(ROWS * 32 + 255) / 256, blk, 0, stream>>>(qext, (float*)nullptr);

    // --- k_ext = ckv @ [Wkup | Wkr] (N=2176), rope kr cols + entry 512..575 ---
    gemm_bt<false, true><<<dim3(LDX / 128, ROWS / 128), blk, 0, stream>>>(
        ckvb, KupxT, (float*)nullptr, kext, ROWS, DC, 0, LDX);
    rope_ext<<<(ROWS * 32 + 255) / 256, blk, 0, stream>>>(kext, out1);

    // --- v = ckv @ Wvup; transpose ---
    gemm_bt<false, true><<<dim3(D / 128, ROWS / 128), blk, 0, stream>>>(
        ckvb, WvupT, (float*)nullptr, vb, ROWS, DC, 0, D);
    transpose_v<<<dim3(Tt / 64, D / 64, Bb), blk, 0, stream>>>(vb, vtb);

    // --- attention: split-KV + reduce ---
    attn_split<<<dim3(4, Tt / 64, NH * Bb), blk, 0, stream>>>(
        qext, kext, vtb, opart, mlpart);
    attn_reduce<<<dim3(Tt / 64, NH * Bb), blk, 0, stream>>>(opart, mlpart, aob);

    // --- out0 = ao @ Wo ---
    gemm_bt<true, false><<<dim3(D / 128, ROWS / 128), blk, 0, stream>>>(
        aob, WoT, out0, (__bf16*)nullptr, ROWS, D, D, 0);
}